// Round 1
// baseline (329.579 us; speedup 1.0000x reference)
//
#include <hip/hip_runtime.h>

// Problem constants (reference: T=256, L=32, C=8, B=16, D=512)
#define TT 256
#define LL 32
#define CC 8
#define BB 16
#define DD 512
#define D4 (DD / 4)          // 128 float4 per d-row
#define NCHUNK 16            // 16 chunks of 16 frames each
#define CHUNK 16

// Output layout (floats): fc | fm | fb
#define FC_ELEMS ((long)BB * LL * LL * CC * DD)   // 67,108,864
#define FM_ELEMS ((long)BB * LL * LL * DD)        //  8,388,608
#define FM_OFF   FC_ELEMS
#define FB_OFF   (FC_ELEMS + FM_ELEMS)            // 75,497,472

// Workspace layout (floats): csum [B][16][D] | S [B][257][D]
#define CSUM_FLOATS ((long)BB * NCHUNK * DD)      // 131,072
#define S_ROWS      (TT + 1)                      // 257
#define S_OFF_FLOATS CSUM_FLOATS

// ---------------------------------------------------------------------------
// Kernel A: per-chunk partial sums. csum[b][chunk][d] = sum_{i<16} f[b, 16*chunk+i, d]
// Grid: B*16*D threads, d fastest -> fully coalesced.
__global__ __launch_bounds__(256) void chunk_sum_kernel(
    const float* __restrict__ f, float* __restrict__ csum) {
  int tid = blockIdx.x * blockDim.x + threadIdx.x;   // 0 .. B*16*D-1
  int d = tid & (DD - 1);
  int chunk = (tid >> 9) & (NCHUNK - 1);
  int b = tid >> 13;
  const float* fp = f + ((long)(b * TT + chunk * CHUNK)) * DD + d;
  float s = 0.f;
#pragma unroll
  for (int i = 0; i < CHUNK; ++i) s += fp[(long)i * DD];
  csum[tid] = s;
}

// ---------------------------------------------------------------------------
// Kernel B: exclusive prefix-sum table S[b][p][d] (p in [0,256]) + fb transpose.
// Each thread owns (b, d, chunk): offset = sum of csum for chunks < mine
// (uniform-length loop per block, no divergence), then serial scan of 16 f
// values, writing S[chunk*16+1 .. chunk*16+16]. chunk 0 also writes S[0]=0.
// fb[b][d][t]: each thread writes its 16 consecutive t as 4x float4 (one
// aligned 64B run per thread -> full-line write combining in L2).
__global__ __launch_bounds__(256) void scan_kernel(
    const float* __restrict__ f, const float* __restrict__ csum,
    float* __restrict__ S, float* __restrict__ fb) {
  int tid = blockIdx.x * blockDim.x + threadIdx.x;
  int d = tid & (DD - 1);
  int chunk = (tid >> 9) & (NCHUNK - 1);
  int b = tid >> 13;

  const float* cp = csum + (long)b * NCHUNK * DD + d;
  float off = 0.f;
  for (int i = 0; i < chunk; ++i) off += cp[(long)i * DD];

  const float* fp = f + ((long)(b * TT + chunk * CHUNK)) * DD + d;
  float* Sp = S + ((long)b * S_ROWS + chunk * CHUNK) * DD + d;
  if (chunk == 0) Sp[0] = 0.f;   // S[b][0][d]

  float vals[CHUNK];
  float acc = off;
#pragma unroll
  for (int i = 0; i < CHUNK; ++i) {
    float x = fp[(long)i * DD];
    vals[i] = x;
    acc += x;
    Sp[(long)(i + 1) * DD] = acc;
  }

  // fb transpose write: fb[((b*D + d)*T) + chunk*16 ... +16)
  float4* fbp = (float4*)(fb + ((long)(b * DD + d)) * TT + chunk * CHUNK);
#pragma unroll
  for (int i = 0; i < 4; ++i) {
    float4 v;
    v.x = vals[4 * i + 0];
    v.y = vals[4 * i + 1];
    v.z = vals[4 * i + 2];
    v.w = vals[4 * i + 3];
    fbp[i] = v;
  }
}

// ---------------------------------------------------------------------------
// Kernel C: fc + fm from prefix-sum differences.
// One block per (b, l, m); 128 threads, each owns one float4 d-chunk.
// fc[b,l,m,c,:] = S[8l + (c+1)w] - S[8l + c*w], w = m-l+1
// fm[b,l,m,:]   = S[8l + 8w]     - S[8l]
// l > m: all zeros (d_out is poisoned 0xAA before every timed launch).
__global__ __launch_bounds__(128) void fc_fm_kernel(
    const float* __restrict__ S, float* __restrict__ out) {
  int m = blockIdx.x;
  int l = blockIdx.y;
  int b = blockIdx.z;
  int d4 = threadIdx.x;  // 0..127

  float4* outv = (float4*)out;
  long blm = (long)((b * LL + l) * LL + m);
  long fc_base = blm * CC * D4;               // in float4 units
  long fm_base = FM_OFF / 4 + blm * D4;

  if (l > m) {
    float4 z = {0.f, 0.f, 0.f, 0.f};
#pragma unroll
    for (int c = 0; c < CC; ++c) outv[fc_base + (long)c * D4 + d4] = z;
    outv[fm_base + d4] = z;
    return;
  }

  int w = m - l + 1;
  const float4* S4 = (const float4*)S;
  long srow = (long)b * S_ROWS;  // row index base (rows of D floats)

  float4 s[9];
#pragma unroll
  for (int c = 0; c <= 8; ++c) {
    int p = 8 * l + c * w;
    s[c] = S4[(srow + p) * D4 + d4];
  }

#pragma unroll
  for (int c = 0; c < CC; ++c) {
    float4 v;
    v.x = s[c + 1].x - s[c].x;
    v.y = s[c + 1].y - s[c].y;
    v.z = s[c + 1].z - s[c].z;
    v.w = s[c + 1].w - s[c].w;
    outv[fc_base + (long)c * D4 + d4] = v;
  }
  float4 vm;
  vm.x = s[8].x - s[0].x;
  vm.y = s[8].y - s[0].y;
  vm.z = s[8].z - s[0].z;
  vm.w = s[8].w - s[0].w;
  outv[fm_base + d4] = vm;
}

// ---------------------------------------------------------------------------
extern "C" void kernel_launch(void* const* d_in, const int* in_sizes, int n_in,
                              void* d_out, int out_size, void* d_ws, size_t ws_size,
                              hipStream_t stream) {
  const float* f = (const float*)d_in[0];
  // d_in[1] is Wc — its effect is fully encoded in the closed-form ranges.
  float* out = (float*)d_out;

  float* csum = (float*)d_ws;                    // 131,072 floats = 512 KB
  float* S = (float*)d_ws + S_OFF_FLOATS;        // 2,105,344 floats = 8.4 MB

  float* fb = out + FB_OFF;

  {
    int total = BB * NCHUNK * DD;  // 131072
    chunk_sum_kernel<<<total / 256, 256, 0, stream>>>(f, csum);
    scan_kernel<<<total / 256, 256, 0, stream>>>(f, csum, S, fb);
  }
  {
    dim3 grid(LL, LL, BB);  // (m, l, b) = 16384 blocks
    fc_fm_kernel<<<grid, 128, 0, stream>>>(S, out);
  }
}

// Round 2
// 324.015 us; speedup vs baseline: 1.0172x; 1.0172x over previous
//
#include <hip/hip_runtime.h>

// Problem constants (reference: T=256, L=32, C=8, B=16, D=512)
#define TT 256
#define LL 32
#define CC 8
#define BB 16
#define DD 512
#define D4 (DD / 4)          // 128 float4 per d-row
#define NCHUNK 16            // 16 chunks of 16 frames each
#define CHUNK 16

// Output layout (floats): fc | fm | fb
#define FC_ELEMS ((long)BB * LL * LL * CC * DD)   // 67,108,864
#define FM_ELEMS ((long)BB * LL * LL * DD)        //  8,388,608
#define FM_OFF   FC_ELEMS
#define FB_OFF   (FC_ELEMS + FM_ELEMS)            // 75,497,472

// Workspace layout (floats): csum [B][16][D] | S [B][257][D]
#define CSUM_FLOATS ((long)BB * NCHUNK * DD)      // 131,072
#define S_ROWS      (TT + 1)                      // 257
#define S_OFF_FLOATS CSUM_FLOATS

__device__ __forceinline__ float4 f4add(float4 a, float4 b) {
  return make_float4(a.x + b.x, a.y + b.y, a.z + b.z, a.w + b.w);
}
__device__ __forceinline__ float4 f4sub(float4 a, float4 b) {
  return make_float4(a.x - b.x, a.y - b.y, a.z - b.z, a.w - b.w);
}

// ---------------------------------------------------------------------------
// Kernel A (float4): csum[b][chunk][d4] = sum_{i<16} f[b, 16*chunk+i, d4]
// B*16*D4 = 32768 threads, d4 fastest -> coalesced 16B/lane loads.
__global__ __launch_bounds__(256) void chunk_sum_kernel(
    const float4* __restrict__ f4, float4* __restrict__ csum4) {
  int tid = blockIdx.x * blockDim.x + threadIdx.x;   // 0 .. 32767
  int d4 = tid & (D4 - 1);
  int chunk = (tid >> 7) & (NCHUNK - 1);
  int b = tid >> 11;
  const float4* fp = f4 + (long)(b * TT + chunk * CHUNK) * D4 + d4;
  float4 s = make_float4(0.f, 0.f, 0.f, 0.f);
#pragma unroll
  for (int i = 0; i < CHUNK; ++i) s = f4add(s, fp[(long)i * D4]);
  csum4[tid] = s;
}

// ---------------------------------------------------------------------------
// Kernel B (float4): exclusive prefix table S[b][p][d] (p in [0,256]) + fb.
// Thread owns (b, chunk, d4): offset = sum of csum for chunks < mine, then
// serial scan of 16 f rows writing S rows chunk*16+1 .. chunk*16+16.
// fb[b][d][t]: register transpose of the 16 staged f values -> 16B stores.
__global__ __launch_bounds__(256) void scan_kernel(
    const float4* __restrict__ f4, const float4* __restrict__ csum4,
    float4* __restrict__ S4, float4* __restrict__ fb4) {
  int tid = blockIdx.x * blockDim.x + threadIdx.x;
  int d4 = tid & (D4 - 1);
  int chunk = (tid >> 7) & (NCHUNK - 1);
  int b = tid >> 11;

  const float4* cp = csum4 + (long)b * NCHUNK * D4 + d4;
  float4 acc = make_float4(0.f, 0.f, 0.f, 0.f);
  for (int i = 0; i < chunk; ++i) acc = f4add(acc, cp[(long)i * D4]);

  const float4* fp = f4 + (long)(b * TT + chunk * CHUNK) * D4 + d4;
  float4* Sp = S4 + ((long)b * S_ROWS + chunk * CHUNK) * D4 + d4;
  if (chunk == 0) Sp[0] = make_float4(0.f, 0.f, 0.f, 0.f);

  float4 vals[CHUNK];
#pragma unroll
  for (int i = 0; i < CHUNK; ++i) {
    vals[i] = fp[(long)i * D4];
    acc = f4add(acc, vals[i]);
    Sp[(long)(i + 1) * D4] = acc;
  }

  // fb[b][d][t]: this thread owns d = 4*d4..4*d4+3, t = chunk*16..+15.
  const float* v = (const float*)vals;  // v[4*i + dd] = f[t=i][d=4*d4+dd]
#pragma unroll
  for (int dd = 0; dd < 4; ++dd) {
    float4* fbp = fb4 + ((long)(b * DD + 4 * d4 + dd) * TT + chunk * CHUNK) / 4;
#pragma unroll
    for (int j = 0; j < 4; ++j) {
      fbp[j] = make_float4(v[(4 * j + 0) * 4 + dd], v[(4 * j + 1) * 4 + dd],
                           v[(4 * j + 2) * 4 + dd], v[(4 * j + 3) * 4 + dd]);
    }
  }
}

// ---------------------------------------------------------------------------
// Kernel C: fc + fm from prefix differences, XCD-locality swizzle.
// 16384 blocks; assuming round-robin block->XCD dispatch, block i runs on
// XCD i&7. Remap so XCD k handles only b in {2k, 2k+1}: S working set per
// XCD = 2 * 514 KB ~= 1 MB < 4 MiB L2 -> S reads stay L2-resident.
// fc[b,l,m,c,:] = S[8l+(c+1)w] - S[8l+c*w], w = m-l+1; fm = S[8l+8w]-S[8l].
// l > m: write zeros (d_out is poisoned 0xAA before every timed launch).
__global__ __launch_bounds__(128) void fc_fm_kernel(
    const float* __restrict__ S, float* __restrict__ out) {
  int i = blockIdx.x;
  int vblk = ((i & 7) << 11) | (i >> 3);  // XCD-contiguous index
  int b = vblk >> 10;
  int l = (vblk >> 5) & (LL - 1);
  int m = vblk & (LL - 1);
  int d4 = threadIdx.x;  // 0..127

  float4* outv = (float4*)out;
  long blm = (long)((b * LL + l) * LL + m);
  long fc_base = blm * CC * D4;               // in float4 units
  long fm_base = FM_OFF / 4 + blm * D4;

  if (l > m) {
    float4 z = make_float4(0.f, 0.f, 0.f, 0.f);
#pragma unroll
    for (int c = 0; c < CC; ++c) outv[fc_base + (long)c * D4 + d4] = z;
    outv[fm_base + d4] = z;
    return;
  }

  int w = m - l + 1;
  const float4* S4 = (const float4*)S;
  long srow = (long)b * S_ROWS;

  float4 s[9];
#pragma unroll
  for (int c = 0; c <= 8; ++c) {
    int p = 8 * l + c * w;
    s[c] = S4[(srow + p) * D4 + d4];
  }

#pragma unroll
  for (int c = 0; c < CC; ++c)
    outv[fc_base + (long)c * D4 + d4] = f4sub(s[c + 1], s[c]);
  outv[fm_base + d4] = f4sub(s[8], s[0]);
}

// ---------------------------------------------------------------------------
extern "C" void kernel_launch(void* const* d_in, const int* in_sizes, int n_in,
                              void* d_out, int out_size, void* d_ws, size_t ws_size,
                              hipStream_t stream) {
  const float4* f4 = (const float4*)d_in[0];
  // d_in[1] is Wc — fully encoded in the closed-form index ranges.
  float* out = (float*)d_out;

  float4* csum4 = (float4*)d_ws;                              // 512 KB
  float4* S4 = (float4*)((float*)d_ws + S_OFF_FLOATS);        // 8.4 MB
  float4* fb4 = (float4*)(out + FB_OFF);

  {
    int total4 = BB * NCHUNK * D4;  // 32768 threads
    chunk_sum_kernel<<<total4 / 256, 256, 0, stream>>>(f4, csum4);
    scan_kernel<<<total4 / 256, 256, 0, stream>>>(f4, csum4, S4, fb4);
  }
  {
    fc_fm_kernel<<<BB * LL * LL, 128, 0, stream>>>((const float*)S4, out);
  }
}